// Round 5
// baseline (294.471 us; speedup 1.0000x reference)
//
#include <hip/hip_runtime.h>

// Problem constants
#define BATCH 16384
#define KEYD  64
#define DDIM  128
#define UDIM  128
#define MODES 32

typedef __attribute__((ext_vector_type(8))) short bf16x8;   // 8 bf16 in 4 VGPRs
typedef __attribute__((ext_vector_type(4))) float f32x4;

__device__ __forceinline__ unsigned short f2bf(float f) {
  unsigned u = __float_as_uint(f);
  unsigned r = (u + 0x7FFFu + ((u >> 16) & 1u)) >> 16;  // RNE bf16
  return (unsigned short)r;
}

__device__ __forceinline__ void gld_lds16(const void* g, void* l) {
  __builtin_amdgcn_global_load_lds(
      (const __attribute__((address_space(1))) unsigned int*)g,
      (__attribute__((address_space(3))) unsigned int*)l, 16, 0, 0);
}

// ---------------------------------------------------------------------------
// Fused prep (one dispatch) — unchanged proven version:
//  blocks [0,512): sim softmax (32 rows/block) + x->bf16.
//  blocks [512,770): cast kernels+biases to bf16 in MFMA-B fragment layout
//    kb16[m][kblk][u][j] = kernels[m][kblk*8+j][u] -> every B-fragment is a
//    contiguous 16B chunk (global_load_lds width-16 friendly).
// ---------------------------------------------------------------------------
__global__ __launch_bounds__(256) void prep_all(
    const float* __restrict__ key, const float* __restrict__ x,
    const float* __restrict__ sens, const float* __restrict__ keys_map,
    const float* __restrict__ kernels, const float* __restrict__ biases,
    float* __restrict__ sim, unsigned short* __restrict__ x16,
    unsigned short* __restrict__ kb16, unsigned short* __restrict__ bb16) {
  const int t = threadIdx.x;
  const int bid = blockIdx.x;

  if (bid < BATCH / 32) {
    __shared__ float kr[32][KEYD];  // 32 key rows, 8KB
    *(float4*)(&kr[0][0] + t * 4) =
        *(const float4*)(key + (long)bid * 32 * KEYD + t * 4);
    *(float4*)(&kr[0][0] + 1024 + t * 4) =
        *(const float4*)(key + (long)bid * 32 * KEYD + 1024 + t * 4);

    const int lane = t & 63, wave = t >> 6;
    const int m = lane & 31, h = lane >> 5;
    float kreg[32];  // this lane's half of mode m's key row
    {
      const float* kmp = keys_map + m * KEYD + h * 32;
      #pragma unroll
      for (int j = 0; j < 32; j += 4) {
        const float4 v = *(const float4*)(kmp + j);
        kreg[j] = v.x; kreg[j + 1] = v.y; kreg[j + 2] = v.z; kreg[j + 3] = v.w;
      }
    }
    const float sv = sens[m];
    __syncthreads();

    #pragma unroll
    for (int rr = 0; rr < 8; ++rr) {
      const int rl = wave * 8 + rr;
      const long row = (long)bid * 32 + rl;

      float d2h = 0.f;
      #pragma unroll
      for (int j = 0; j < 32; j += 2) {
        const float2 kv = *(const float2*)(&kr[rl][h * 32 + j]);
        float a = kv.x - kreg[j], b = kv.y - kreg[j + 1];
        d2h += a * a + b * b;
      }
      float d2 = d2h + __shfl_xor(d2h, 32, 64);
      float logit = sv / (sqrtf(d2) + 1.0f);
      float mx = logit;
      #pragma unroll
      for (int off = 16; off > 0; off >>= 1) mx = fmaxf(mx, __shfl_xor(mx, off, 64));
      float e = __expf(logit - mx);
      float s = e;
      #pragma unroll
      for (int off = 16; off > 0; off >>= 1) s += __shfl_xor(s, off, 64);
      if (h == 0) sim[row * MODES + m] = e / s;

      const float2 xv = *(const float2*)(x + row * DDIM + lane * 2);
      ushort2 o; o.x = f2bf(xv.x); o.y = f2bf(xv.y);
      *(ushort2*)(x16 + row * DDIM + lane * 2) = o;
    }
  } else {
    int tt = (bid - BATCH / 32) * 256 + t;
    if (tt < MODES * 16 * UDIM) {
      int u = tt & 127, kb = (tt >> 7) & 15, m = tt >> 11;
      const float* src = kernels + (long)((m * 16 + kb) * 8) * UDIM + u;
      ushort4 lo, hi;
      lo.x = f2bf(src[0 * UDIM]); lo.y = f2bf(src[1 * UDIM]);
      lo.z = f2bf(src[2 * UDIM]); lo.w = f2bf(src[3 * UDIM]);
      hi.x = f2bf(src[4 * UDIM]); hi.y = f2bf(src[5 * UDIM]);
      hi.z = f2bf(src[6 * UDIM]); hi.w = f2bf(src[7 * UDIM]);
      *(ushort4*)(kb16 + (long)tt * 8) = lo;
      *(ushort4*)(kb16 + (long)tt * 8 + 4) = hi;
    } else {
      int tb = tt - MODES * 16 * UDIM;
      int u = tb & 127, kb = tb >> 7;
      const float* src = biases + kb * 8 * UDIM + u;
      ushort4 lo, hi;
      lo.x = f2bf(src[0 * UDIM]); lo.y = f2bf(src[1 * UDIM]);
      lo.z = f2bf(src[2 * UDIM]); lo.w = f2bf(src[3 * UDIM]);
      hi.x = f2bf(src[4 * UDIM]); hi.y = f2bf(src[5 * UDIM]);
      hi.z = f2bf(src[6 * UDIM]); hi.w = f2bf(src[7 * UDIM]);
      *(ushort4*)(bb16 + (long)tb * 8) = lo;
      *(ushort4*)(bb16 + (long)tb * 8 + 4) = hi;
    }
  }
}

// ---------------------------------------------------------------------------
// All-modes fused GEMM, R3's proven block-wide contiguous staging + T3/T4
// counted-vmcnt pipeline (never drain to 0 in the loop):
//   grid (BATCH/64, 2), 256 thr (4 waves). Block = 64 rows x 64 cols.
//   LDS: ring of 4 single-mode buffers (4 x 16 KB) + simT 8 KB = 72 KB
//   -> 2 blocks/CU. Depth-3 prefetch: per wave 12 gld_lds in flight.
//   Per mode: WAITV(8) [my oldest 4 done] -> raw s_barrier [all waves'
//   mode-mi chunks in LDS; recycled slot fully consumed] -> issue stage of
//   mode mi+3 -> ds_read bF -> 16 MFMA (setprio-wrapped) -> sim-scale.
//   Staging chunks identical to R3: 1 KB contiguous per gld_lds, block-wide.
// ---------------------------------------------------------------------------
#define MODE_STRIDE (16 * UDIM * 8)  // shorts per mode in kb16 (32 KB)

#define WAITV(n) asm volatile("s_waitcnt vmcnt(" #n ")" ::: "memory")

__global__ __launch_bounds__(256, 2) void gemm_fused(
    const unsigned short* __restrict__ x16, const unsigned short* __restrict__ kb16,
    const unsigned short* __restrict__ bb16, const float* __restrict__ sim,
    float* __restrict__ out) {
  __shared__ alignas(16) unsigned short bsh[4][16 * 64 * 8];  // 4 ring slots x 16 KB
  __shared__ float simT[MODES][64];                           // 8 KB

  const int t = threadIdx.x;
  const int lane = t & 63, w = t >> 6;
  const int q = lane >> 4, l16 = lane & 15;
  const long bm = (long)blockIdx.x * 64;
  const int ch = blockIdx.y;      // column half: global cols [ch*64, ch*64+64)
  const int uc = w * 16 + l16;    // local col 0..63

  // stage sim transposed: 64 rows x 32 modes; 256 thr x 8 floats, coalesced
  {
    const int r = t >> 2, mg = (t & 3) * 8;
    const float4 v0 = *(const float4*)(sim + (bm + r) * MODES + mg);
    const float4 v1 = *(const float4*)(sim + (bm + r) * MODES + mg + 4);
    simT[mg + 0][r] = v0.x; simT[mg + 1][r] = v0.y;
    simT[mg + 2][r] = v0.z; simT[mg + 3][r] = v0.w;
    simT[mg + 4][r] = v1.x; simT[mg + 5][r] = v1.y;
    simT[mg + 6][r] = v1.z; simT[mg + 7][r] = v1.w;
  }
  __syncthreads();

  // A fragments: full 64-row x K=128 tile in registers (64 VGPRs).
  // A[row = rt*16 + l16][k = ks*32 + q*8 + j]
  bf16x8 aF[4][4];
  #pragma unroll
  for (int rt = 0; rt < 4; ++rt)
    #pragma unroll
    for (int ks = 0; ks < 4; ++ks)
      aF[rt][ks] = *(const bf16x8*)(x16 + (bm + rt * 16 + l16) * DDIM + ks * 32 + q * 8);

  // keep aF loads program-ordered before the staging DMAs (vmcnt accounting)
  asm volatile("" ::: "memory");

  // Stage one mode (16 KB = this block's 64-col half): 16 chunks of 1 KB,
  // wave w stages chunks [w*4, w*4+4) -> contiguous 4 KB global per wave,
  // 1 KB fully-contiguous per gld_lds (64 lanes x 16B). 4 vmem ops/wave.
#define STAGE(m, p) do {                                                        \
    _Pragma("unroll")                                                           \
    for (int i = 0; i < 4; ++i) {                                               \
      const int c = w * 4 + i;  /* kb row */                                    \
      gld_lds16(kb16 + (long)(m) * MODE_STRIDE + c * (UDIM * 8) + ch * (64 * 8) \
                    + lane * 8,                                                 \
                &bsh[p][(c * 64 + lane) * 8]);                                  \
    }                                                                           \
  } while (0)

  // prologue: fill 3 of 4 ring slots (12 DMA ops in flight per wave)
  STAGE(0, 0); STAGE(1, 1); STAGE(2, 2);

  f32x4 acc[4] = {};

  #pragma unroll
  for (int mi = 0; mi < MODES; ++mi) {
    // counted wait: my mode-mi chunks done; up to 8 (modes mi+1, mi+2) remain
    if (mi <= 29) WAITV(8);
    else if (mi == 30) WAITV(4);
    else WAITV(0);
    // all waves' mode-mi chunks now in LDS; recycled slot consumed by all
    __builtin_amdgcn_s_barrier();
    asm volatile("" ::: "memory");

    if (mi < MODES - 3) STAGE(mi + 3, (mi + 3) & 3);  // refill ring slot

    const unsigned short* bs = &bsh[mi & 3][0];
    bf16x8 bF[4];  // [ks]: fragment (kb = ks*4+q, u = uc), contiguous 16B
    #pragma unroll
    for (int ks = 0; ks < 4; ++ks)
      bF[ks] = *(const bf16x8*)&bs[(((ks * 4 + q) * 64) + uc) * 8];

    __builtin_amdgcn_s_setprio(1);
    f32x4 tmp[4] = {};
    #pragma unroll
    for (int ks = 0; ks < 4; ++ks)
      #pragma unroll
      for (int rt = 0; rt < 4; ++rt)
        tmp[rt] = __builtin_amdgcn_mfma_f32_16x16x32_bf16(aF[rt][ks], bF[ks], tmp[rt], 0, 0, 0);
    __builtin_amdgcn_s_setprio(0);

    #pragma unroll
    for (int rt = 0; rt < 4; ++rt) {
      const f32x4 sv = *(const f32x4*)&simT[mi][rt * 16 + q * 4];
      acc[rt] += sv * tmp[rt];
    }
  }
#undef STAGE

  // bias term: one K=32 MFMA round (A = sim rows in bf16, B = biases)
  {
    const bf16x8 bb = *(const bf16x8*)(bb16 + ((long)q * UDIM + ch * 64 + uc) * 8);
    #pragma unroll
    for (int rt = 0; rt < 4; ++rt) {
      const float* sp = sim + (bm + rt * 16 + l16) * MODES + q * 8;
      const float4 sv0 = *(const float4*)(sp);
      const float4 sv1 = *(const float4*)(sp + 4);
      bf16x8 sF;
      sF[0] = (short)f2bf(sv0.x); sF[1] = (short)f2bf(sv0.y);
      sF[2] = (short)f2bf(sv0.z); sF[3] = (short)f2bf(sv0.w);
      sF[4] = (short)f2bf(sv1.x); sF[5] = (short)f2bf(sv1.y);
      sF[6] = (short)f2bf(sv1.z); sF[7] = (short)f2bf(sv1.w);
      acc[rt] = __builtin_amdgcn_mfma_f32_16x16x32_bf16(sF, bb, acc[rt], 0, 0, 0);
    }
  }

  // epilogue: direct store, 1/MODES folded in; each out element written once
  #pragma unroll
  for (int rt = 0; rt < 4; ++rt) {
    const long row = bm + rt * 16 + q * 4;
    #pragma unroll
    for (int r = 0; r < 4; ++r)
      out[(row + r) * UDIM + ch * 64 + uc] = acc[rt][r] * (1.0f / MODES);
  }
}

extern "C" void kernel_launch(void* const* d_in, const int* in_sizes, int n_in,
                              void* d_out, int out_size, void* d_ws, size_t ws_size,
                              hipStream_t stream) {
  const float* key      = (const float*)d_in[0];
  const float* x        = (const float*)d_in[1];
  const float* sens     = (const float*)d_in[2];
  const float* keys_map = (const float*)d_in[3];
  const float* kernels  = (const float*)d_in[4];
  const float* biases   = (const float*)d_in[5];
  float* out = (float*)d_out;

  char* ws = (char*)d_ws;
  float*          sim  = (float*)ws;                          // 2 MB
  unsigned short* x16  = (unsigned short*)(ws + (2u << 20));  // 4 MB
  unsigned short* kb16 = (unsigned short*)(ws + (6u << 20));  // 1 MB
  unsigned short* bb16 = (unsigned short*)(ws + (7u << 20));  // 8 KB

  prep_all<<<BATCH / 32 + 258, 256, 0, stream>>>(
      key, x, sens, keys_map, kernels, biases, sim, x16, kb16, bb16);
  gemm_fused<<<dim3(BATCH / 64, 2), 256, 0, stream>>>(x16, kb16, bb16, sim, out);
}

// Round 6
// 106.585 us; speedup vs baseline: 2.7628x; 2.7628x over previous
//
#include <hip/hip_runtime.h>

// Problem constants
#define BATCH 16384
#define KEYD  64
#define DDIM  128
#define UDIM  128
#define MODES 32

typedef __attribute__((ext_vector_type(8))) short bf16x8;   // 8 bf16 in 4 VGPRs
typedef __attribute__((ext_vector_type(4))) float f32x4;

__device__ __forceinline__ unsigned short f2bf(float f) {
  unsigned u = __float_as_uint(f);
  unsigned r = (u + 0x7FFFu + ((u >> 16) & 1u)) >> 16;  // RNE bf16
  return (unsigned short)r;
}

__device__ __forceinline__ void gld_lds16(const void* g, void* l) {
  __builtin_amdgcn_global_load_lds(
      (const __attribute__((address_space(1))) unsigned int*)g,
      (__attribute__((address_space(3))) unsigned int*)l, 16, 0, 0);
}

// ---------------------------------------------------------------------------
// Fused prep — proven version + one addition: also writes simT[mode][row]
// (transposed sim) so the GEMM can broadcast-load per-mode scales without
// touching LDS. Transpose goes through a small padded LDS tile so the
// global write stays coalesced.
// ---------------------------------------------------------------------------
__global__ __launch_bounds__(256) void prep_all(
    const float* __restrict__ key, const float* __restrict__ x,
    const float* __restrict__ sens, const float* __restrict__ keys_map,
    const float* __restrict__ kernels, const float* __restrict__ biases,
    float* __restrict__ sim, float* __restrict__ simT,
    unsigned short* __restrict__ x16,
    unsigned short* __restrict__ kb16, unsigned short* __restrict__ bb16) {
  const int t = threadIdx.x;
  const int bid = blockIdx.x;

  if (bid < BATCH / 32) {
    __shared__ float kr[32][KEYD];   // 32 key rows, 8KB
    __shared__ float sims[32][33];   // [mode][local row], +1 pad
    *(float4*)(&kr[0][0] + t * 4) =
        *(const float4*)(key + (long)bid * 32 * KEYD + t * 4);
    *(float4*)(&kr[0][0] + 1024 + t * 4) =
        *(const float4*)(key + (long)bid * 32 * KEYD + 1024 + t * 4);

    const int lane = t & 63, wave = t >> 6;
    const int m = lane & 31, h = lane >> 5;
    float kreg[32];  // this lane's half of mode m's key row
    {
      const float* kmp = keys_map + m * KEYD + h * 32;
      #pragma unroll
      for (int j = 0; j < 32; j += 4) {
        const float4 v = *(const float4*)(kmp + j);
        kreg[j] = v.x; kreg[j + 1] = v.y; kreg[j + 2] = v.z; kreg[j + 3] = v.w;
      }
    }
    const float sv = sens[m];
    __syncthreads();

    #pragma unroll
    for (int rr = 0; rr < 8; ++rr) {
      const int rl = wave * 8 + rr;
      const long row = (long)bid * 32 + rl;

      float d2h = 0.f;
      #pragma unroll
      for (int j = 0; j < 32; j += 2) {
        const float2 kv = *(const float2*)(&kr[rl][h * 32 + j]);
        float a = kv.x - kreg[j], b = kv.y - kreg[j + 1];
        d2h += a * a + b * b;
      }
      float d2 = d2h + __shfl_xor(d2h, 32, 64);
      float logit = sv / (sqrtf(d2) + 1.0f);
      float mx = logit;
      #pragma unroll
      for (int off = 16; off > 0; off >>= 1) mx = fmaxf(mx, __shfl_xor(mx, off, 64));
      float e = __expf(logit - mx);
      float s = e;
      #pragma unroll
      for (int off = 16; off > 0; off >>= 1) s += __shfl_xor(s, off, 64);
      if (h == 0) {
        const float p = e / s;
        sim[row * MODES + m] = p;
        sims[m][rl] = p;
      }

      const float2 xv = *(const float2*)(x + row * DDIM + lane * 2);
      ushort2 o; o.x = f2bf(xv.x); o.y = f2bf(xv.y);
      *(ushort2*)(x16 + row * DDIM + lane * 2) = o;
    }

    __syncthreads();
    // coalesced simT write: thread t -> mode t>>3, rows (t&7)*4 .. +3
    {
      const int m2 = t >> 3, r0 = (t & 7) * 4;
      float4 v;
      v.x = sims[m2][r0 + 0]; v.y = sims[m2][r0 + 1];
      v.z = sims[m2][r0 + 2]; v.w = sims[m2][r0 + 3];
      *(float4*)(simT + (long)m2 * BATCH + (long)bid * 32 + r0) = v;
    }
  } else {
    int tt = (bid - BATCH / 32) * 256 + t;
    if (tt < MODES * 16 * UDIM) {
      int u = tt & 127, kb = (tt >> 7) & 15, m = tt >> 11;
      const float* src = kernels + (long)((m * 16 + kb) * 8) * UDIM + u;
      ushort4 lo, hi;
      lo.x = f2bf(src[0 * UDIM]); lo.y = f2bf(src[1 * UDIM]);
      lo.z = f2bf(src[2 * UDIM]); lo.w = f2bf(src[3 * UDIM]);
      hi.x = f2bf(src[4 * UDIM]); hi.y = f2bf(src[5 * UDIM]);
      hi.z = f2bf(src[6 * UDIM]); hi.w = f2bf(src[7 * UDIM]);
      *(ushort4*)(kb16 + (long)tt * 8) = lo;
      *(ushort4*)(kb16 + (long)tt * 8 + 4) = hi;
    } else {
      int tb = tt - MODES * 16 * UDIM;
      int u = tb & 127, kb = tb >> 7;
      const float* src = biases + kb * 8 * UDIM + u;
      ushort4 lo, hi;
      lo.x = f2bf(src[0 * UDIM]); lo.y = f2bf(src[1 * UDIM]);
      lo.z = f2bf(src[2 * UDIM]); lo.w = f2bf(src[3 * UDIM]);
      hi.x = f2bf(src[4 * UDIM]); hi.y = f2bf(src[5 * UDIM]);
      hi.z = f2bf(src[6 * UDIM]); hi.w = f2bf(src[7 * UDIM]);
      *(ushort4*)(bb16 + (long)tb * 8) = lo;
      *(ushort4*)(bb16 + (long)tb * 8 + 4) = hi;
    }
  }
}

// ---------------------------------------------------------------------------
// Strip-resident GEMM: each block owns 16 output columns x 512 rows and
// stages its ENTIRE B slice once (2 x 64 KB halves) — kb16 request volume
// drops 268 MB -> 32 MB chip-wide, and there are only 3 barriers total, so
// the poisoned-LLC re-read pathology (R1/R4/R5) cannot occur.
//   grid 256 = 8 col-strips x 32 row-groups (bid = strip*32 + group, so the
//   8 strips of a row-group share an XCD under round-robin dispatch -> each
//   x16 panel fetched ~once per XCD). 256 thr, 4 waves; wave = 128 rows.
//   LDS: bshB 64 KB only (one half of B: 16 modes). Half 1 is prefetched to
//   REGISTERS during half-0 compute (T14) and ds_written after a barrier.
//   sim scales: f32x4 broadcast loads from global simT, software-pipelined
//   even/odd (svA/svB) to cover latency at 1 wave/SIMD.
//   MFMA: 2 halves x 16 modes x 8 rt x 4 ks = 1024 per wave.
// ---------------------------------------------------------------------------
__global__ __launch_bounds__(256, 1) void gemm_strip(
    const unsigned short* __restrict__ x16, const unsigned short* __restrict__ kb16,
    const unsigned short* __restrict__ bb16, const float* __restrict__ sim,
    const float* __restrict__ simT, float* __restrict__ out) {
  // [chunk c = m_local*16 + kb][col 16][8 shorts] : 64 KB
  __shared__ alignas(16) unsigned short bshB[256 * 16 * 8];

  const int t = threadIdx.x;
  const int lane = t & 63, w = t >> 6;
  const int q = lane >> 4, l16 = lane & 15;
  const int bid = blockIdx.x;
  const int group = bid & 31, strip = bid >> 5;
  const long bm = (long)group * 512;
  const int wrow = w * 128;

  // ---- issue stage of half 0 (modes 0..15): 64 gld_lds, 1 KB each ----
  // instruction j = i*4 + w covers chunks 4j..4j+3; lane supplies 16B of
  // chunk 4j + (lane>>4), col (lane&15). LDS dest is lane-linear.
  #pragma unroll
  for (int i = 0; i < 16; ++i) {
    const int j = i * 4 + w;
    const int c = 4 * j + (lane >> 4);
    const int m_l = c >> 4, kb = c & 15;
    gld_lds16(kb16 + ((long)m_l * 16 + kb) * (UDIM * 8) + (strip * 16 + (lane & 15)) * 8,
              &bshB[(c * 16 + (lane & 15)) * 8]);
  }

  // ---- A fragments: 128 rows x K=128 per wave, in registers (128 VGPR) ----
  bf16x8 aF[8][4];
  #pragma unroll
  for (int rt = 0; rt < 8; ++rt)
    #pragma unroll
    for (int ks = 0; ks < 4; ++ks)
      aF[rt][ks] = *(const bf16x8*)(x16 + (bm + wrow + rt * 16 + l16) * DDIM + ks * 32 + q * 8);

  __syncthreads();  // barrier 1: half0 staged (drain), aF in regs

  // ---- prefetch half 1 (modes 16..31) into registers (64 VGPR) ----
  bf16x8 pf[16];
  #pragma unroll
  for (int i = 0; i < 16; ++i) {
    const int j = i * 4 + w;
    const int c = 4 * j + (lane >> 4);
    const int m_l = c >> 4, kb = c & 15;
    pf[i] = *(const bf16x8*)(kb16 + ((long)(16 + m_l) * 16 + kb) * (UDIM * 8)
                             + (strip * 16 + (lane & 15)) * 8);
  }

  f32x4 acc[8] = {};
  const float* svbase = simT + bm + wrow + q * 4;

#define LOAD_SV(dst, mg)                                                        \
  { _Pragma("unroll")                                                           \
    for (int rt = 0; rt < 8; ++rt)                                              \
      dst[rt] = *(const f32x4*)(svbase + (long)(mg) * BATCH + rt * 16); }

#define COMPUTE_MODE(ml, SV)                                                    \
  { bf16x8 bF[4];                                                               \
    _Pragma("unroll")                                                           \
    for (int ks = 0; ks < 4; ++ks)                                              \
      bF[ks] = *(const bf16x8*)&bshB[(((ml) * 16 + ks * 4 + q) * 16 + l16) * 8];\
    _Pragma("unroll")                                                           \
    for (int rt = 0; rt < 8; ++rt) {                                            \
      f32x4 tmp = {};                                                           \
      _Pragma("unroll")                                                         \
      for (int ks = 0; ks < 4; ++ks)                                            \
        tmp = __builtin_amdgcn_mfma_f32_16x16x32_bf16(aF[rt][ks], bF[ks], tmp, 0, 0, 0); \
      acc[rt] += SV[rt] * tmp;                                                  \
    } }

  for (int h = 0; h < 2; ++h) {
    if (h == 1) {
      __syncthreads();  // barrier 2: all waves done reading half 0
      #pragma unroll
      for (int i = 0; i < 16; ++i) {
        const int j = i * 4 + w;
        const int c = 4 * j + (lane >> 4);
        *(bf16x8*)&bshB[(c * 16 + (lane & 15)) * 8] = pf[i];
      }
      __syncthreads();  // barrier 3: half 1 visible
    }
    f32x4 svA[8], svB[8];
    LOAD_SV(svA, h * 16);
    #pragma unroll 2
    for (int ml = 0; ml < 16; ml += 2) {
      LOAD_SV(svB, h * 16 + ml + 1);
      COMPUTE_MODE(ml, svA);
      if (ml + 2 < 16) LOAD_SV(svA, h * 16 + ml + 2);
      COMPUTE_MODE(ml + 1, svB);
    }
  }
#undef LOAD_SV
#undef COMPUTE_MODE

  // ---- bias: one K=32 MFMA round (A = sim rows bf16, B = biases) ----
  {
    const bf16x8 bb = *(const bf16x8*)(bb16 + ((long)q * UDIM + strip * 16 + l16) * 8);
    #pragma unroll
    for (int rt = 0; rt < 8; ++rt) {
      const float* sp = sim + (bm + wrow + rt * 16 + l16) * MODES + q * 8;
      const float4 sv0 = *(const float4*)(sp);
      const float4 sv1 = *(const float4*)(sp + 4);
      bf16x8 sF;
      sF[0] = (short)f2bf(sv0.x); sF[1] = (short)f2bf(sv0.y);
      sF[2] = (short)f2bf(sv0.z); sF[3] = (short)f2bf(sv0.w);
      sF[4] = (short)f2bf(sv1.x); sF[5] = (short)f2bf(sv1.y);
      sF[6] = (short)f2bf(sv1.z); sF[7] = (short)f2bf(sv1.w);
      acc[rt] = __builtin_amdgcn_mfma_f32_16x16x32_bf16(sF, bb, acc[rt], 0, 0, 0);
    }
  }

  // ---- epilogue: direct store, 1/MODES folded in ----
  #pragma unroll
  for (int rt = 0; rt < 8; ++rt) {
    const long row = bm + wrow + rt * 16 + q * 4;
    #pragma unroll
    for (int r = 0; r < 4; ++r)
      out[(row + r) * UDIM + strip * 16 + l16] = acc[rt][r] * (1.0f / MODES);
  }
}

extern "C" void kernel_launch(void* const* d_in, const int* in_sizes, int n_in,
                              void* d_out, int out_size, void* d_ws, size_t ws_size,
                              hipStream_t stream) {
  const float* key      = (const float*)d_in[0];
  const float* x        = (const float*)d_in[1];
  const float* sens     = (const float*)d_in[2];
  const float* keys_map = (const float*)d_in[3];
  const float* kernels  = (const float*)d_in[4];
  const float* biases   = (const float*)d_in[5];
  float* out = (float*)d_out;

  char* ws = (char*)d_ws;
  float*          sim  = (float*)ws;                          // 2 MB
  unsigned short* x16  = (unsigned short*)(ws + (2u << 20));  // 4 MB
  unsigned short* kb16 = (unsigned short*)(ws + (6u << 20));  // 1 MB
  unsigned short* bb16 = (unsigned short*)(ws + (7u << 20));  // 8 KB
  float*          simT = (float*)(ws + (8u << 20));           // 2 MB

  prep_all<<<BATCH / 32 + 258, 256, 0, stream>>>(
      key, x, sens, keys_map, kernels, biases, sim, simT, x16, kb16, bb16);
  gemm_strip<<<dim3(256), 256, 0, stream>>>(x16, kb16, bb16, sim, simT, out);
}